// Round 11
// baseline (885.949 us; speedup 1.0000x reference)
//
#include <hip/hip_runtime.h>
#include <hip/hip_cooperative_groups.h>
#include <math.h>

namespace cg = cooperative_groups;

typedef unsigned short UST;
typedef __attribute__((ext_vector_type(8))) short bf16x8;
typedef __attribute__((ext_vector_type(4))) float f32x4;

#define BB 4
#define LL 1024
#define IND 256
#define DD 512
#define HH 8
#define FFD 2048
#define NT (BB*LL)

__device__ __forceinline__ float bf2f(UST u){ return __uint_as_float(((unsigned)u)<<16); }
__device__ __forceinline__ UST f2bf(float f){
  unsigned u = __float_as_uint(f);
  u += 0x7FFFu + ((u>>16)&1u);
  return (UST)(u>>16);
}
__device__ __forceinline__ float ldF(const void* p, long i, int isf32){
  return isf32 ? ((const float*)p)[i] : bf2f(((const UST*)p)[i]);
}
__device__ __forceinline__ bool ldMask(const void* p, long i, int fm){
  if (fm==0) return ((const int*)p)[i] != 0;
  if (fm==1) return ((const unsigned char*)p)[i] != 0;
  if (fm==2) return ((const UST*)p)[i] != 0;
  return ((const float*)p)[i] != 0.f;
}
__device__ __forceinline__ f32x4 mfma16(bf16x8 a, bf16x8 b, f32x4 c){
  return __builtin_amdgcn_mfma_f32_16x16x32_bf16(a, b, c, 0, 0, 0);
}
__device__ __forceinline__ void gld16(const void* g, void* l){
  __builtin_amdgcn_global_load_lds((const __attribute__((address_space(1))) unsigned int*)g,
                                   (__attribute__((address_space(3))) unsigned int*)l, 16, 0, 0);
}

struct MegaArgs {
  const void* src[11]; UST* dst[11]; int n[11];
  const UST* xh; const void* mask; const void* adj; const void* lsp;
  const void* ln1g; const void* ln1b; const void* ln2g; const void* ln2b;
  UST *bias2, *qkv, *vT, *xn, *ctx, *hb;
  UST *xbf, *wfuse, *bfuse, *ipw, *ipb, *outw, *outb, *w1, *b1, *w2, *b2;
  float *xf, *x2, *parts;
  void* dout;
  int* flags;
};

// ---------------- device: dtype detect (wave 0 of a block -> sF[2]) ----------------
__device__ __forceinline__ void detect_dev(const UST* xh, const unsigned int* mw, int* sF){
  int t = threadIdx.x;
  if (t < 64){
    int e0 = (xh[t] >> 7) & 0xFF;
    int e1 = (xh[64+t] >> 7) & 0xFF;
    int f32 = __any((e0 >= 140) || (e1 >= 140)) ? 1 : 0;
    unsigned v = mw[t];
    int w01   = __all(v <= 1u) ? 1 : 0;
    unsigned lo = v & 0xFFFFu, hi = v >> 16;
    int half  = __all((lo==0u||lo==0x3F80u) && (hi==0u||hi==0x3F80u)) ? 1 : 0;
    int wordF = __all(v==0u || v==0x3F800000u) ? 1 : 0;
    int byteB = __all((v & 0xFEFEFEFEu) == 0u) ? 1 : 0;
    if (t == 0){
      sF[0] = f32;
      sF[1] = w01 ? 0 : (half ? (wordF ? 3 : 2) : (byteB ? 1 : 0));
    }
  }
}

// ---------------- device: prep item (bias row in attn-frag layout, or cvt chunk) ----
__device__ __forceinline__ void prep_item(char* smemc, int fF, int fM,
    const MegaArgs& a, int idx){
  int t = threadIdx.x;
  UST* sTile = (UST*)smemc;            // 2KB
  int* sAll  = (int*)(smemc + 2048);
  __syncthreads();                     // guard smem reuse
  if (idx < BB*LL){
    int row = idx;
    int i = row & (LL-1);
    long base = (long)row * LL;
    int j0 = t*4;
    bool mv[4];
    if (fM == 0){
      int4 m4 = *(const int4*)((const int*)a.mask + base + j0);
      mv[0]=m4.x!=0; mv[1]=m4.y!=0; mv[2]=m4.z!=0; mv[3]=m4.w!=0;
    } else {
      #pragma unroll
      for (int k=0;k<4;++k) mv[k] = ldMask(a.mask, base + j0 + k, fM);
    }
    float a4[4];
    if (fF){
      float4 av = *(const float4*)((const float*)a.adj + base + j0);
      a4[0]=av.x; a4[1]=av.y; a4[2]=av.z; a4[3]=av.w;
    } else {
      const UST* ap = (const UST*)a.adj + base + j0;
      #pragma unroll
      for (int k=0;k<4;++k) a4[k] = bf2f(ap[k]);
    }
    int my = (mv[0]&&mv[1]&&mv[2]&&mv[3]) ? 1 : 0;
    int wa = __all(my);
    int w = t >> 6;
    if ((t & 63) == 0) sAll[w] = wa;
    __syncthreads();
    int rowAll = sAll[0] & sAll[1] & sAll[2] & sAll[3];
    float es = expf(ldF(a.lsp, 0, fF));
    UST o4[4];
    #pragma unroll
    for (int k = 0; k < 4; ++k){
      int j = j0 + k;
      float av = fminf(fmaxf(a4[k], 0.f), 1.f);
      bool eff = mv[k] && !((rowAll != 0) && (j == i));
      o4[k] = f2bf(((eff ? -10000.f : 0.f) + es * av) * 1.44269504f);
    }
    *(int2*)&sTile[j0] = *(const int2*)o4;
    __syncthreads();
    int kt = t >> 4, l15 = t & 15;
    UST g4[4];
    #pragma unroll
    for (int ni=0; ni<4; ++ni) g4[ni] = sTile[kt*64 + ni*16 + l15];
    int b = row >> 10, rr = row & 1023;
    int qt = rr >> 6, q = rr & 63;
    int w2 = q >> 4, qd = (q >> 2) & 3, r = q & 3;
    long dst = ((long)((b*16 + qt)*16 + kt))*4096 + w2*1024 + (qd*16 + l15)*16 + r*4;
    *(int2*)(a.bias2 + dst) = *(const int2*)g4;
  } else {
    int cb = idx - BB*LL;
    int ti = cb >> 9, xi = cb & 511;
    int n = a.n[ti];
    long i8 = ((long)xi*256 + t)*8;
    if (i8 < n){
      const void* s = a.src[ti]; UST* d = a.dst[ti];
      if (fF){
        const float4* sf = (const float4*)s;
        float4 a0 = sf[i8>>2], a1 = sf[(i8>>2)+1];
        UST o[8] = { f2bf(a0.x),f2bf(a0.y),f2bf(a0.z),f2bf(a0.w),
                     f2bf(a1.x),f2bf(a1.y),f2bf(a1.z),f2bf(a1.w) };
        *(int4*)(d+i8) = *(const int4*)o;
      } else {
        ((int4*)d)[i8>>3] = ((const int4*)s)[i8>>3];
      }
    }
  }
}

// ---------------- device: one GEMM tile (chunk-transposed LDS, BK=64, dbuf) --------
template<int TM, int TN, int ACT, int RES, int OUTMODE>
__device__ __forceinline__ void gemm_tile(char* smemc, int fF,
    const UST* __restrict__ A, const UST* __restrict__ Bw, const UST* __restrict__ bias,
    const float* __restrict__ resid, void* Cout,
    int M, int N, int K, int Ks, int m0, int n0, int zslice){
  constexpr int MI = TM/32, NI = TN/32;
  UST* sA0 = (UST*)smemc;                       // [2][TM*64]
  UST* sB0 = (UST*)(smemc + 2*TM*64*2);         // [2][TN*64]
  int t = threadIdx.x, w = t>>6, lane = t&63, l15 = lane&15, qd = lane>>4;
  int zoff = zslice * Ks;
  int wm = (w&1)*(TM/2), wn = (w>>1)*(TN/2);
  f32x4 acc[MI][NI];
  #pragma unroll
  for (int mi=0; mi<MI; ++mi)
    #pragma unroll
    for (int ni=0; ni<NI; ++ni){ acc[mi][ni][0]=0;acc[mi][ni][1]=0;acc[mi][ni][2]=0;acc[mi][ni][3]=0; }
  int sRow = lane&7, sCol = (lane>>3)*8;
  const UST* aS = A + (long)(m0 + w*(TM/4) + sRow)*K + sCol + zoff;
  const UST* bS = Bw + (long)(n0 + w*(TN/4) + sRow)*K + sCol + zoff;
  auto stage = [&](int buf, int k0){
    #pragma unroll
    for (int c=0;c<MI;++c) gld16(aS + (long)c*8*K + k0, (char*)(sA0 + buf*(TM*64) + (w*(TM/4)+c*8)*64));
    #pragma unroll
    for (int c=0;c<NI;++c) gld16(bS + (long)c*8*K + k0, (char*)(sB0 + buf*(TN*64) + (w*(TN/4)+c*8)*64));
  };
  __syncthreads();                    // guard smem reuse from previous phase/tile
  stage(0, 0);
  for (int k0 = 0; k0 < Ks; k0 += 64){
    int cur = (k0>>6)&1, nxt = cur^1;
    __syncthreads();
    if (k0 + 64 < Ks) stage(nxt, k0+64);
    #pragma unroll
    for (int ks=0; ks<2; ++ks){
      bf16x8 afr[MI], bfr[NI];
      #pragma unroll
      for (int mi=0; mi<MI; ++mi){
        int R = wm + mi*16 + l15;
        afr[mi] = *(const bf16x8*)&sA0[cur*(TM*64) + (R>>3)*512 + (ks*4+qd)*64 + (R&7)*8];
      }
      #pragma unroll
      for (int ni=0; ni<NI; ++ni){
        int R = wn + ni*16 + l15;
        bfr[ni] = *(const bf16x8*)&sB0[cur*(TN*64) + (R>>3)*512 + (ks*4+qd)*64 + (R&7)*8];
      }
      #pragma unroll
      for (int mi=0; mi<MI; ++mi)
        #pragma unroll
        for (int ni=0; ni<NI; ++ni)
          acc[mi][ni] = mfma16(afr[mi], bfr[ni], acc[mi][ni]);
    }
  }
  if (OUTMODE == 3){
    float* P = (float*)Cout + (size_t)zslice * M * N;
    #pragma unroll
    for (int mi=0; mi<MI; ++mi)
      #pragma unroll
      for (int ni=0; ni<NI; ++ni){
        int gc = n0 + wn + ni*16 + l15;
        #pragma unroll
        for (int r=0; r<4; ++r){
          int grow = m0 + wm + mi*16 + qd*4 + r;
          P[(long)grow*N + gc] = acc[mi][ni][r];
        }
      }
    return;
  }
  int outF32 = (OUTMODE==1) || (OUTMODE==2 && fF);
  #pragma unroll
  for (int mi=0; mi<MI; ++mi){
    #pragma unroll
    for (int ni=0; ni<NI; ++ni){
      int gc = n0 + wn + ni*16 + l15;
      float bv = bf2f(bias[gc]);
      #pragma unroll
      for (int r=0; r<4; ++r){
        int grow = m0 + wm + mi*16 + qd*4 + r;
        float c = acc[mi][ni][r] + bv;
        if (ACT) c = 0.5f*c*(1.f+erff(c*0.70710678118654752f));
        long oi = (long)grow*N + gc;
        if (RES) c += resid[oi];
        if (outF32) ((float*)Cout)[oi] = c;
        else ((UST*)Cout)[oi] = f2bf(c);
      }
    }
  }
}

// ---------------- device: LayerNorm row ----------------
__device__ __forceinline__ void ln_row(char* smemc, int fF, const float* xin,
    const void* gp, const void* bp, UST* xout, int row){
  float* rs = (float*)smemc;
  float* rq = rs + 4;
  int t = threadIdx.x;
  const float* xr = xin + (long)row * DD;
  float v0 = xr[t], v1 = xr[t+256];
  float s = v0+v1, q = v0*v0 + v1*v1;
  #pragma unroll
  for (int off=1; off<64; off<<=1){ s += __shfl_xor(s,off,64); q += __shfl_xor(q,off,64); }
  int w = t>>6;
  __syncthreads();
  if ((t&63)==0){ rs[w]=s; rq[w]=q; }
  __syncthreads();
  float S = rs[0]+rs[1]+rs[2]+rs[3];
  float Q = rq[0]+rq[1]+rq[2]+rq[3];
  float mean = S * (1.f/DD);
  float var  = fmaxf(Q * (1.f/DD) - mean*mean, 0.f);
  float ri = rsqrtf(var + 1e-5f);
  float g0 = ldF(gp, t, fF), b0 = ldF(bp, t, fF);
  float g1 = ldF(gp, t+256, fF), b1 = ldF(bp, t+256, fF);
  xout[(long)row*DD + t]     = f2bf((v0-mean)*ri*g0 + b0);
  xout[(long)row*DD + t+256] = f2bf((v1-mean)*ri*g1 + b1);
}

// ---------------- device: V repack item ----------------
__device__ __forceinline__ void repack_item(const UST* __restrict__ qkv,
    UST* __restrict__ vT, int id){
  int bh = id & 31, qt = id >> 5;
  int b = bh >> 3, h = bh & 7;
  int t = threadIdx.x, w = t >> 6, lane = t & 63;
  int token = qt*64 + lane;
  const UST* src = qkv + ((long)(b*LL + token))*1536 + 1024 + h*64;
  #pragma unroll
  for (int c = 0; c < 2; ++c){
    int ch = w*2 + c;
    union { int4 v; UST u[8]; } uu;
    uu.v = *(const int4*)(src + ch*8);
    #pragma unroll
    for (int i = 0; i < 8; ++i)
      vT[((long)(bh*64 + ch*8 + i))*LL + token] = uu.u[i];
  }
}

// ---------------- device: attention tile (no-max softmax, bias regs, dbuf) ---------
__device__ __forceinline__ void attn_tile(char* smemc, const UST* __restrict__ qkv,
    const UST* __restrict__ vT, const UST* __restrict__ bias2, UST* __restrict__ ctx, int id){
  UST* sK = (UST*)smemc;             // [2][2][2048]
  UST* sV = (UST*)(smemc + 16384);   // [2][2][2048]
  UST* sP = (UST*)(smemc + 32768);   // [4][16*72]
  int b = id & 3, h = (id>>2) & 7, qt = id >> 5;
  int bh = b*HH + h;
  int q0 = qt*64;
  int t = threadIdx.x, w = t>>6, lane = t&63, l15 = lane&15, qd = lane>>4;
  UST* myP = sP + w*16*72;

  const UST* qrow = qkv + ((long)(b*LL + q0 + w*16 + l15))*1536 + h*64;
  bf16x8 qf0 = *(const bf16x8*)(qrow + qd*8);
  bf16x8 qf1 = *(const bf16x8*)(qrow + 32 + qd*8);

  const UST* kS = qkv + (long)(b*LL + w*16 + l15)*1536 + 512 + h*64 + qd*8;
  const UST* vS = vT + (long)(bh*64 + w*16 + l15)*LL + qd*8;
  const UST* bP = bias2 + ((long)((b*16 + qt)*16))*4096 + w*1024 + lane*16;

  f32x4 o[4]; float lsum[4];
  #pragma unroll
  for (int i=0;i<4;i++){ o[i][0]=0;o[i][1]=0;o[i][2]=0;o[i][3]=0; lsum[i]=0.f; }
  const float C1 = 0.18033688f;   // 0.125*log2e; bias pre-scaled by log2e

  auto stage = [&](int buf, int k0){
    gld16(kS + (long)k0*1536,      (char*)sK + (buf*2+0)*4096 + w*1024);
    gld16(kS + (long)k0*1536 + 32, (char*)sK + (buf*2+1)*4096 + w*1024);
    gld16(vS + k0,                 (char*)sV + (buf*2+0)*4096 + w*1024);
    gld16(vS + k0 + 32,            (char*)sV + (buf*2+1)*4096 + w*1024);
  };
  __syncthreads();                    // guard smem reuse from previous phase
  stage(0, 0);
  int4 bc0 = *(const int4*)(bP);
  int4 bc1 = *(const int4*)(bP + 8);

  for (int kt = 0; kt < 16; ++kt){
    int cur = kt&1, nxt = cur^1;
    int k0 = kt*64;
    __syncthreads();
    if (kt < 15) stage(nxt, k0+64);
    int kn = (kt < 15 ? kt+1 : 15);
    int4 bn0 = *(const int4*)(bP + (long)kn*4096);
    int4 bn1 = *(const int4*)(bP + (long)kn*4096 + 8);
    f32x4 s4[4];
    #pragma unroll
    for (int i=0;i<4;i++){ s4[i][0]=0;s4[i][1]=0;s4[i][2]=0;s4[i][3]=0; }
    #pragma unroll
    for (int ni=0; ni<4; ++ni){
      bf16x8 kf0 = *(const bf16x8*)&sK[(cur*2+0)*2048 + ni*512 + qd*128 + l15*8];
      bf16x8 kf1 = *(const bf16x8*)&sK[(cur*2+1)*2048 + ni*512 + qd*128 + l15*8];
      s4[ni] = mfma16(qf0, kf0, s4[ni]);
      s4[ni] = mfma16(qf1, kf1, s4[ni]);
    }
    union { int4 v; UST u[8]; } B0, B1;
    B0.v = bc0; B1.v = bc1;
    float p[4][4];
    #pragma unroll
    for (int ni=0; ni<4; ++ni){
      #pragma unroll
      for (int r=0; r<4; ++r){
        UST bu = (r < 2) ? B0.u[r*4 + ni] : B1.u[(r&1)*4 + ni];
        p[ni][r] = exp2f(fmaf(s4[ni][r], C1, bf2f(bu)));
      }
    }
    bc0 = bn0; bc1 = bn1;
    #pragma unroll
    for (int r=0; r<4; ++r)
      lsum[r] += (p[0][r]+p[1][r]) + (p[2][r]+p[3][r]);
    #pragma unroll
    for (int ni=0; ni<4; ++ni)
      #pragma unroll
      for (int r=0; r<4; ++r) myP[(qd*4+r)*72 + ni*16 + l15] = f2bf(p[ni][r]);
    bf16x8 pf0 = *(const bf16x8*)&myP[l15*72 + qd*8];
    bf16x8 pf1 = *(const bf16x8*)&myP[l15*72 + 32 + qd*8];
    #pragma unroll
    for (int dn=0; dn<4; ++dn){
      bf16x8 vf0 = *(const bf16x8*)&sV[(cur*2+0)*2048 + dn*512 + qd*128 + l15*8];
      bf16x8 vf1 = *(const bf16x8*)&sV[(cur*2+1)*2048 + dn*512 + qd*128 + l15*8];
      o[dn] = mfma16(pf0, vf0, o[dn]);
      o[dn] = mfma16(pf1, vf1, o[dn]);
    }
  }
  float linv[4];
  #pragma unroll
  for (int r=0; r<4; ++r){
    float s = lsum[r];
    #pragma unroll
    for (int off=1; off<16; off<<=1) s += __shfl_xor(s, off, 64);
    linv[r] = 1.f / s;
  }
  #pragma unroll
  for (int dn=0; dn<4; ++dn){
    #pragma unroll
    for (int r=0; r<4; ++r){
      long oi = ((long)(b*LL + q0 + w*16 + qd*4 + r))*DD + h*64 + dn*16 + l15;
      ctx[oi] = f2bf(o[dn][r] * linv[r]);
    }
  }
}

// ---------------- device: split-K reduce item ----------------
__device__ __forceinline__ void reduce_item(int fF, const float* __restrict__ parts,
    const UST* __restrict__ bias, const float* __restrict__ resid,
    void* __restrict__ dout, int blk){
  const long S = (long)NT*DD;
  long e = ((long)blk*256 + threadIdx.x)*4;
  float4 a = *(const float4*)(parts + e);
  float4 b = *(const float4*)(parts + S + e);
  float4 c = *(const float4*)(parts + 2*S + e);
  float4 d = *(const float4*)(parts + 3*S + e);
  float4 r = *(const float4*)(resid + e);
  int gc = (int)(e & (DD-1));
  float v[4] = { a.x+b.x+c.x+d.x + bf2f(bias[gc+0]) + r.x,
                 a.y+b.y+c.y+d.y + bf2f(bias[gc+1]) + r.y,
                 a.z+b.z+c.z+d.z + bf2f(bias[gc+2]) + r.z,
                 a.w+b.w+c.w+d.w + bf2f(bias[gc+3]) + r.w };
  if (fF){
    *(float4*)((float*)dout + e) = *(const float4*)v;
  } else {
    UST o4[4] = { f2bf(v[0]), f2bf(v[1]), f2bf(v[2]), f2bf(v[3]) };
    *(int2*)((UST*)dout + e) = *(const int2*)o4;
  }
}

// ================= MEGA KERNEL: all phases, grid.sync between =================
__global__ __launch_bounds__(256, 2) void mega_k(MegaArgs a){
  __shared__ char smem[65536];
  cg::grid_group grid = cg::this_grid();
  int bid = blockIdx.x;
  int* sF = (int*)(smem + 8192);
  detect_dev(a.xh, (const unsigned int*)a.mask, sF);
  __syncthreads();
  int fF = sF[0], fM = sF[1];
  if (bid == 0 && threadIdx.x == 0){ a.flags[0] = fF; a.flags[1] = fM; }

  // P0: prep (bias rows 0..4095, cvt chunks 4096..9727) — 19 items/block
  for (int idx = bid; idx < BB*LL + 11*512; idx += 512)
    prep_item(smem, fF, fM, a, idx);
  grid.sync();
  // P1: fuse  xf = x*Wf^T + bf (fp32)
  gemm_tile<64,64,0,0,1>(smem, fF, a.xbf, a.wfuse, a.bfuse, nullptr, a.xf,
                         NT, DD, IND, IND, (bid>>3)*64, (bid&7)*64, 0);
  grid.sync();
  // P2: ln1
  for (int i=0;i<8;++i) ln_row(smem, fF, a.xf, a.ln1g, a.ln1b, a.xn, bid + i*512);
  grid.sync();
  // P3: qkv
  for (int idx = bid; idx < 768; idx += 512)
    gemm_tile<64,128,0,0,0>(smem, fF, a.xn, a.ipw, a.ipb, nullptr, a.qkv,
                            NT, 3*DD, DD, DD, (idx & 63)*64, (idx >> 6)*128, 0);
  grid.sync();
  // P4: repack V
  repack_item(a.qkv, a.vT, bid);
  grid.sync();
  // P5: attention
  attn_tile(smem, a.qkv, a.vT, a.bias2, a.ctx, bid);
  grid.sync();
  // P6: attn out + residual (fp32 x2)
  gemm_tile<64,64,0,1,1>(smem, fF, a.ctx, a.outw, a.outb, a.xf, a.x2,
                         NT, DD, DD, DD, (bid>>3)*64, (bid&7)*64, 0);
  grid.sync();
  // P7: ln2
  for (int i=0;i<8;++i) ln_row(smem, fF, a.x2, a.ln2g, a.ln2b, a.xn, bid + i*512);
  grid.sync();
  // P8: ffn1 gelu (128x128)
  gemm_tile<128,128,1,0,0>(smem, fF, a.xn, a.w1, a.b1, nullptr, a.hb,
                           NT, FFD, DD, DD, (bid>>4)*128, (bid&15)*128, 0);
  grid.sync();
  // P9: ffn2 split-K=4 partials
  { int z = bid >> 7, mn = bid & 127;
    gemm_tile<128,128,0,0,3>(smem, fF, a.hb, a.w2, a.b2, nullptr, a.parts,
                             NT, DD, FFD, FFD/4, (mn>>2)*128, (mn&3)*128, z); }
  grid.sync();
  // P10: reduce + bias + resid -> out
  for (int i=0;i<4;++i) reduce_item(fF, a.parts, a.b2, a.x2, a.dout, bid + i*512);
}

// ================= standalone fallback kernels (wrap the same device code) =========
__global__ __launch_bounds__(256) void prep_k(MegaArgs a){
  __shared__ char smem[4096];
  int* sF = (int*)(smem + 2560);
  detect_dev(a.xh, (const unsigned int*)a.mask, sF);
  __syncthreads();
  int fF = sF[0], fM = sF[1];
  if (blockIdx.x == 0 && threadIdx.x == 0){ a.flags[0] = fF; a.flags[1] = fM; }
  prep_item(smem, fF, fM, a, blockIdx.x);
}

template<int TM, int TN, int ACT, int RES, int OUTMODE>
__global__ __launch_bounds__(256) void gemm3_k(const int* flags,
    const UST* A, const UST* Bw, const UST* bias, const float* resid, void* Cout,
    int M, int N, int K, int Ks){
  __shared__ char smem[2*TM*64*2 + 2*TN*64*2];
  int fF = (OUTMODE==2) ? flags[0] : 0;
  gemm_tile<TM,TN,ACT,RES,OUTMODE>(smem, fF, A, Bw, bias, resid, Cout,
      M, N, K, Ks, blockIdx.x*TM, blockIdx.y*TN, blockIdx.z);
}

__global__ __launch_bounds__(256) void ln_k(const int* flags, const float* xin,
    const void* gp, const void* bp, UST* xout){
  __shared__ char smem[64];
  ln_row(smem, flags[0], xin, gp, bp, xout, blockIdx.x);
}

__global__ __launch_bounds__(256) void repack_v(const UST* qkv, UST* vT){
  repack_item(qkv, vT, blockIdx.x);
}

__global__ __launch_bounds__(256) void attn_k(const UST* qkv, const UST* vT,
    const UST* bias2, UST* ctx){
  __shared__ char smem[41472];
  attn_tile(smem, qkv, vT, bias2, ctx, blockIdx.x);
}

__global__ __launch_bounds__(256) void reduce4_k(const int* flags, const float* parts,
    const UST* bias, const float* resid, void* dout){
  reduce_item(flags[0], parts, bias, resid, dout, blockIdx.x);
}

extern "C" void kernel_launch(void* const* d_in, const int* in_sizes, int n_in,
                              void* d_out, int out_size, void* d_ws, size_t ws_size,
                              hipStream_t stream){
  char* ws = (char*)d_ws;
  size_t o = 0;
  auto alloc = [&](size_t b){ size_t r = o; o += (b + 255) & ~(size_t)255; return r; };
  int*   flags = (int*)(ws + alloc(256));
  size_t biasOff = alloc(8UL<<20);
  size_t qkvOff  = alloc(12UL<<20);
  UST* biasC = (UST*)(ws + biasOff);
  UST* qkv   = (UST*)(ws + qkvOff);
  UST* hb    = (UST*)(ws + biasOff);        // aliases biasC+qkv (both dead by ffn1)
  UST* vT    = (UST*)(ws + alloc(4UL<<20));
  UST* xbf   = (UST*)(ws + alloc(2UL<<20));
  UST* wfuse = (UST*)(ws + alloc(131072*2));
  UST* bfuse = (UST*)(ws + alloc(1024));
  UST* ipw   = (UST*)(ws + alloc(786432*2));
  UST* ipb   = (UST*)(ws + alloc(3072*2));
  UST* outw  = (UST*)(ws + alloc(262144*2));
  UST* outb  = (UST*)(ws + alloc(1024));
  UST* w1    = (UST*)(ws + alloc(1048576*2));
  UST* b1    = (UST*)(ws + alloc(4096*2));
  UST* w2    = (UST*)(ws + alloc(1048576*2));
  UST* b2    = (UST*)(ws + alloc(1024));
  float* xf  = (float*)(ws + alloc((size_t)NT*DD*4));
  UST* xn    = (UST*)(ws + alloc((size_t)NT*DD*2));
  UST* ctx   = (UST*)(ws + alloc((size_t)NT*DD*2));
  float* x2  = (float*)(ws + alloc((size_t)NT*DD*4));
  size_t partsOff = alloc(4UL*NT*DD*4);     // 33.5MB ffn2 split-K partials
  float* parts = (float*)(ws + partsOff);
  bool fits = (o <= ws_size);

  MegaArgs ma;
  const int srcIdx[11] = {0,3,4,5,6,7,8,13,14,15,16};
  UST* dsts[11] = {xbf,wfuse,bfuse,ipw,ipb,outw,outb,w1,b1,w2,b2};
  const int ns[11] = {NT*IND, DD*IND, DD, 3*DD*DD, 3*DD, DD*DD, DD, FFD*DD, FFD, DD*FFD, DD};
  for (int i=0;i<11;i++){ ma.src[i]=d_in[srcIdx[i]]; ma.dst[i]=dsts[i]; ma.n[i]=ns[i]; }
  ma.xh = (const UST*)d_in[0];
  ma.mask = d_in[1]; ma.adj = d_in[2]; ma.lsp = d_in[17];
  ma.ln1g = d_in[9]; ma.ln1b = d_in[10]; ma.ln2g = d_in[11]; ma.ln2b = d_in[12];
  ma.bias2 = biasC; ma.qkv = qkv; ma.vT = vT; ma.xn = xn; ma.ctx = ctx; ma.hb = hb;
  ma.xbf=xbf; ma.wfuse=wfuse; ma.bfuse=bfuse; ma.ipw=ipw; ma.ipb=ipb;
  ma.outw=outw; ma.outb=outb; ma.w1=w1; ma.b1=b1; ma.w2=w2; ma.b2=b2;
  ma.xf = xf; ma.x2 = x2; ma.parts = parts;
  ma.dout = d_out; ma.flags = flags;

  hipError_t err = hipErrorUnknown;
  if (fits){
    void* params[] = { (void*)&ma };
    err = hipLaunchCooperativeKernel((const void*)mega_k, dim3(512), dim3(256),
                                     params, 0, stream);
  }
  if (err != hipSuccess){
    // fallback: R10 multi-kernel path (identical math via shared device functions)
    prep_k<<<BB*LL + 11*512, 256, 0, stream>>>(ma);
    gemm3_k<64,64,0,0,1><<<dim3(64,8), 256, 0, stream>>>(flags, xbf, wfuse, bfuse, nullptr, xf, NT, DD, IND, IND);
    ln_k<<<NT, 256, 0, stream>>>(flags, xf, d_in[9], d_in[10], xn);
    gemm3_k<64,128,0,0,0><<<dim3(64,12), 256, 0, stream>>>(flags, xn, ipw, ipb, nullptr, qkv, NT, 3*DD, DD, DD);
    repack_v<<<512, 256, 0, stream>>>(qkv, vT);
    attn_k<<<512, 256, 0, stream>>>(qkv, vT, biasC, ctx);
    gemm3_k<64,64,0,1,1><<<dim3(64,8), 256, 0, stream>>>(flags, ctx, outw, outb, xf, x2, NT, DD, DD, DD);
    ln_k<<<NT, 256, 0, stream>>>(flags, x2, d_in[11], d_in[12], xn);
    gemm3_k<128,128,1,0,0><<<dim3(32,16), 256, 0, stream>>>(flags, xn, w1, b1, nullptr, hb, NT, FFD, DD, DD);
    if (fits){
      gemm3_k<128,128,0,0,3><<<dim3(32,4,4), 256, 0, stream>>>(flags, hb, w2, b2, nullptr, parts, NT, DD, FFD, FFD/4);
      reduce4_k<<<(NT*DD)/1024, 256, 0, stream>>>(flags, parts, b2, x2, d_out);
    } else {
      gemm3_k<64,64,0,1,2><<<dim3(64,8), 256, 0, stream>>>(flags, hb, w2, b2, x2, d_out, NT, DD, FFD, FFD);
    }
  }
}